// Round 1
// baseline (163.289 us; speedup 1.0000x reference)
//
#include <hip/hip_runtime.h>
#include <hip/hip_bf16.h>
#include <math.h>

#define N0 4096
#define NM1 8192

// ---------------------------------------------------------------------------
// butterfly reduce-scatter step: 2*NV values -> NV values, exchanging with
// lane^d. After the step, lanes with (lane&d)==0 hold sums of the lower half,
// (lane&d)==1 the upper half.
// ---------------------------------------------------------------------------
template<int NV>
__device__ __forceinline__ void red_scatter(float* v, const int d, const int lane) {
  const bool up = (lane & d) != 0;
  #pragma unroll
  for (int i = 0; i < NV; ++i) {
    float send = up ? v[i] : v[i + NV];
    float recv = __shfl_xor(send, d);
    float keep = up ? v[i + NV] : v[i];
    v[i] = keep + recv;
  }
}

// ---------------------------------------------------------------------------
// u_partial = b1[rows, m-range] @ x1   (single 16-col chain, no norm)
// grid 1024 = 256 row-groups x 4 m-splits; block 128 (2 waves, 8 rows/wave)
// wave layout: q = lane>>5 (c-half), ml = lane&31 (m-lane); m strided by 32.
// ---------------------------------------------------------------------------
__global__ __launch_bounds__(128)
void b1_matmul_kernel(const float* __restrict__ A,   // [4096][8192]
                      const float* __restrict__ X,   // [8192][16]
                      float* __restrict__ pP)        // [4][4096][16]
{
  __shared__ float4 Bs[2048];                        // 512 m x 4 blocks, 32 KiB
  const int tid  = threadIdx.x;
  const int wv   = tid >> 6;
  const int lane = tid & 63;
  const int q    = lane >> 5;
  const int ml   = lane & 31;
  const int s    = blockIdx.x & 3;
  const int rg   = blockIdx.x >> 2;
  const int row0 = rg * 16 + wv * 8;

  float acc[64];
  #pragma unroll
  for (int i = 0; i < 64; ++i) acc[i] = 0.0f;
  const int j0 = q * 2;

  for (int ch = 0; ch < 4; ++ch) {
    const int mb = s * 2048 + ch * 512;
    __syncthreads();
    #pragma unroll
    for (int k = 0; k < 16; ++k) {
      const int idx = tid + 128 * k;            // < 2048
      const int m = idx >> 2, j = idx & 3;
      Bs[m * 4 + (j ^ ((m >> 1) & 3))] =
          *(const float4*)(X + (size_t)(mb + m) * 16 + j * 4);
    }
    __syncthreads();
    #pragma unroll
    for (int it = 0; it < 4; ++it) {
      float a[8][4];
      #pragma unroll
      for (int r = 0; r < 8; ++r) {
        #pragma unroll
        for (int v = 0; v < 4; ++v)
          a[r][v] = A[(size_t)(row0 + r) * NM1 + mb + it * 128 + ml + 32 * v];
      }
      #pragma unroll
      for (int v = 0; v < 4; ++v) {
        const int mm = it * 128 + ml + 32 * v;
        const int sw = (mm >> 1) & 3;
        const float4 b0 = Bs[mm * 4 + (j0 ^ sw)];
        const float4 b1 = Bs[mm * 4 + ((j0 + 1) ^ sw)];
        #pragma unroll
        for (int r = 0; r < 8; ++r) {
          const float av = a[r][v];
          acc[r*8+0] += av * b0.x;  acc[r*8+1] += av * b0.y;
          acc[r*8+2] += av * b0.z;  acc[r*8+3] += av * b0.w;
          acc[r*8+4] += av * b1.x;  acc[r*8+5] += av * b1.y;
          acc[r*8+6] += av * b1.z;  acc[r*8+7] += av * b1.w;
        }
      }
    }
  }

  // reduce across 32 m-lanes: 64 vals -> 2 per lane
  red_scatter<32>(acc, 1, lane);
  red_scatter<16>(acc, 2, lane);
  red_scatter<8>(acc, 4, lane);
  red_scatter<4>(acc, 8, lane);
  red_scatter<2>(acc, 16, lane);

  const int r  = ((ml & 1) << 2) | (((ml >> 1) & 1) << 1) | ((ml >> 2) & 1);
  const int cb = ((ml >> 3) & 1) * 4 + ((ml >> 4) & 1) * 2;
  float* dst = pP + (size_t)(s * N0 + row0 + r) * 16 + q * 8 + cb;
  *(float2*)dst = make_float2(acc[0], acc[1]);
}

__global__ void finalize_u_kernel(const float* __restrict__ pP,
                                  float* __restrict__ u) {
  const int idx = blockIdx.x * 256 + threadIdx.x;   // < 65536
  u[idx] = pP[idx] + pP[65536 + idx] + pP[131072 + idx] + pP[196608 + idx];
}

// ---------------------------------------------------------------------------
// Fused Chebyshev step partials: for both chains at once,
//   pX/pU[s] = L0[rows, m-range] @ {cx, cu},  pRS[s] = rowsum(L0[rows, m-range])
// grid 1024 = 256 row-groups x 4 m-splits; block 128 (2 waves, 8 rows/wave)
// wave layout: q = lane>>4 (8-col group of the 32 concat cols), ml = lane&15.
// ---------------------------------------------------------------------------
__global__ __launch_bounds__(128)
void cheb_step_kernel(const float* __restrict__ A,    // [4096][4096]
                      const float* __restrict__ cx,   // [4096][16]
                      const float* __restrict__ cu,   // [4096][16]
                      float* __restrict__ pX,         // [4][4096][16]
                      float* __restrict__ pU,         // [4][4096][16]
                      float* __restrict__ pRS)        // [4][4096]
{
  __shared__ float4 Bs[2048];                         // 256 m x 8 blocks, 32 KiB
  const int tid  = threadIdx.x;
  const int wv   = tid >> 6;
  const int lane = tid & 63;
  const int q    = lane >> 4;
  const int ml   = lane & 15;
  const int s    = blockIdx.x & 3;
  const int rg   = blockIdx.x >> 2;
  const int row0 = rg * 16 + wv * 8;

  float acc[64];
  #pragma unroll
  for (int i = 0; i < 64; ++i) acc[i] = 0.0f;
  float rs[8];
  #pragma unroll
  for (int i = 0; i < 8; ++i) rs[i] = 0.0f;
  const int j0 = q * 2;

  for (int ch = 0; ch < 4; ++ch) {
    const int mb = s * 1024 + ch * 256;
    __syncthreads();
    #pragma unroll
    for (int k = 0; k < 16; ++k) {
      const int idx = tid + 128 * k;            // < 2048
      const int m = idx >> 3, j = idx & 7;
      const float* src = (j < 4) ? (cx + (size_t)(mb + m) * 16 + j * 4)
                                 : (cu + (size_t)(mb + m) * 16 + (j - 4) * 4);
      Bs[m * 8 + (j ^ ((m >> 2) & 7))] = *(const float4*)src;
    }
    __syncthreads();
    #pragma unroll
    for (int it = 0; it < 4; ++it) {
      const int mloc = it * 64 + ml * 4;
      float a[8][4];
      #pragma unroll
      for (int r = 0; r < 8; ++r) {
        const float4 t = *(const float4*)(A + (size_t)(row0 + r) * N0 + mb + mloc);
        a[r][0] = t.x; a[r][1] = t.y; a[r][2] = t.z; a[r][3] = t.w;
      }
      #pragma unroll
      for (int v = 0; v < 4; ++v) {
        const int mm = mloc + v;
        const int sw = (mm >> 2) & 7;
        const float4 b0 = Bs[mm * 8 + (j0 ^ sw)];
        const float4 b1 = Bs[mm * 8 + ((j0 + 1) ^ sw)];
        #pragma unroll
        for (int r = 0; r < 8; ++r) {
          const float av = a[r][v];
          acc[r*8+0] += av * b0.x;  acc[r*8+1] += av * b0.y;
          acc[r*8+2] += av * b0.z;  acc[r*8+3] += av * b0.w;
          acc[r*8+4] += av * b1.x;  acc[r*8+5] += av * b1.y;
          acc[r*8+6] += av * b1.z;  acc[r*8+7] += av * b1.w;
          rs[r] += av;
        }
      }
    }
  }

  // reduce across 16 m-lanes: 64 vals -> 4 per lane
  red_scatter<32>(acc, 1, lane);
  red_scatter<16>(acc, 2, lane);
  red_scatter<8>(acc, 4, lane);
  red_scatter<4>(acc, 8, lane);

  // rowsum: 8 vals -> 1 per lane (lanes ml and ml^8 duplicate)
  red_scatter<4>(rs, 1, lane);
  red_scatter<2>(rs, 2, lane);
  red_scatter<1>(rs, 4, lane);
  const float rsum = rs[0] + __shfl_xor(rs[0], 8);

  const int r  = ((ml & 1) << 2) | (((ml >> 1) & 1) << 1) | ((ml >> 2) & 1);
  const int cb = ((ml >> 3) & 1) * 4;
  float* base = (q >> 1) ? pU : pX;
  float* dst = base + (size_t)(s * N0 + row0 + r) * 16 + (q & 1) * 8 + cb;
  *(float4*)dst = make_float4(acc[0], acc[1], acc[2], acc[3]);

  if (q == 0 && ml < 8) pRS[s * N0 + row0 + r] = rsum;
}

// ---------------------------------------------------------------------------
// Sum partials, apply aggr_norm: inv=1/rowsum (nonfinite->0), y=inv*y
// (nonfinite->0). One thread per (row, c), both chains.
// ---------------------------------------------------------------------------
__global__ void normalize_kernel(const float* __restrict__ pX,
                                 const float* __restrict__ pU,
                                 const float* __restrict__ pRS,
                                 float* __restrict__ ox,
                                 float* __restrict__ ou) {
  const int idx = blockIdx.x * 256 + threadIdx.x;   // < 65536
  const int row = idx >> 4;
  float rsv = pRS[row] + pRS[N0 + row] + pRS[2 * N0 + row] + pRS[3 * N0 + row];
  float inv = 1.0f / rsv;
  if (!isfinite(inv)) inv = 0.0f;
  float xv = (pX[idx] + pX[65536 + idx] + pX[131072 + idx] + pX[196608 + idx]) * inv;
  float uv = (pU[idx] + pU[65536 + idx] + pU[131072 + idx] + pU[196608 + idx]) * inv;
  ox[idx] = isfinite(xv) ? xv : 0.0f;
  ou[idx] = isfinite(uv) ? uv : 0.0f;
}

// ---------------------------------------------------------------------------
// y0[n,o] = sum_{i,k} xall[n,i,k] * W[i,o,k];  k order:
//   0: x_0, 1..3: xlap1..3, 4: u, 5..7: ulap1..3
// block: 16 rows x 16 o; grid 256.
// ---------------------------------------------------------------------------
__global__ void einsum_kernel(const float* __restrict__ x0,
                              const float* __restrict__ xl1,
                              const float* __restrict__ xl2,
                              const float* __restrict__ xl3,
                              const float* __restrict__ u,
                              const float* __restrict__ ul1,
                              const float* __restrict__ ul2,
                              const float* __restrict__ ul3,
                              const float* __restrict__ W,   // [16][16][8]
                              float* __restrict__ y) {
  __shared__ float Wl[2048];
  __shared__ float xs[16 * 128];                 // [r][k][i]
  const int t = threadIdx.x;
  const int row0 = blockIdx.x * 16;
  #pragma unroll
  for (int k = 0; k < 8; ++k) Wl[t + 256 * k] = W[t + 256 * k];
  const int r = t >> 4;
  const int i = t & 15;
  const int g = (row0 + r) * 16 + i;
  xs[r * 128 + 0 * 16 + i] = x0[g];
  xs[r * 128 + 1 * 16 + i] = xl1[g];
  xs[r * 128 + 2 * 16 + i] = xl2[g];
  xs[r * 128 + 3 * 16 + i] = xl3[g];
  xs[r * 128 + 4 * 16 + i] = u[g];
  xs[r * 128 + 5 * 16 + i] = ul1[g];
  xs[r * 128 + 6 * 16 + i] = ul2[g];
  xs[r * 128 + 7 * 16 + i] = ul3[g];
  __syncthreads();
  const int o = t & 15;
  float acc = 0.0f;
  #pragma unroll
  for (int ii = 0; ii < 16; ++ii) {
    #pragma unroll
    for (int k = 0; k < 8; ++k)
      acc += xs[r * 128 + k * 16 + ii] * Wl[(ii * 16 + o) * 8 + k];
  }
  y[(row0 + r) * 16 + o] = acc;
}

// ---------------------------------------------------------------------------
extern "C" void kernel_launch(void* const* d_in, const int* in_sizes, int n_in,
                              void* d_out, int out_size, void* d_ws, size_t ws_size,
                              hipStream_t stream) {
  const float* x0 = (const float*)d_in[0];
  const float* x1 = (const float*)d_in[1];
  const float* L0 = (const float*)d_in[3];
  const float* B1 = (const float*)d_in[8];
  const float* W0 = (const float*)d_in[10];

  float* ws  = (float*)d_ws;
  float* u   = ws;                 // 65536
  float* xl1 = ws + 65536;
  float* xl2 = ws + 131072;
  float* xl3 = ws + 196608;
  float* ul1 = ws + 262144;
  float* ul2 = ws + 327680;
  float* ul3 = ws + 393216;
  float* pX  = ws + 458752;        // 4*65536
  float* pU  = ws + 720896;        // 4*65536
  float* pRS = ws + 983040;        // 4*4096

  // u = b1 @ x_1
  b1_matmul_kernel<<<1024, 128, 0, stream>>>(B1, x1, pX);
  finalize_u_kernel<<<256, 256, 0, stream>>>(pX, u);

  // fused two-chain Chebyshev steps
  cheb_step_kernel<<<1024, 128, 0, stream>>>(L0, x0, u, pX, pU, pRS);
  normalize_kernel<<<256, 256, 0, stream>>>(pX, pU, pRS, xl1, ul1);
  cheb_step_kernel<<<1024, 128, 0, stream>>>(L0, xl1, ul1, pX, pU, pRS);
  normalize_kernel<<<256, 256, 0, stream>>>(pX, pU, pRS, xl2, ul2);
  cheb_step_kernel<<<1024, 128, 0, stream>>>(L0, xl2, ul2, pX, pU, pRS);
  normalize_kernel<<<256, 256, 0, stream>>>(pX, pU, pRS, xl3, ul3);

  // y_0 = einsum('nik,iok->no', x_0_all, weight_0)
  einsum_kernel<<<256, 256, 0, stream>>>(x0, xl1, xl2, xl3, u, ul1, ul2, ul3,
                                         W0, (float*)d_out);
}

// Round 2
// 136.502 us; speedup vs baseline: 1.1962x; 1.1962x over previous
//
#include <hip/hip_runtime.h>
#include <hip/hip_bf16.h>
#include <math.h>

#define N0 4096
#define NM1 8192

// ---------------------------------------------------------------------------
// butterfly reduce-scatter step: 2*NV values -> NV values, exchanging with
// lane^d. Lanes with (lane&d)==0 keep lower-half sums, ==1 the upper half.
// ---------------------------------------------------------------------------
template<int NV>
__device__ __forceinline__ void red_scatter(float* v, const int d, const int lane) {
  const bool up = (lane & d) != 0;
  #pragma unroll
  for (int i = 0; i < NV; ++i) {
    float send = up ? v[i] : v[i + NV];
    float recv = __shfl_xor(send, d);
    float keep = up ? v[i + NV] : v[i];
    v[i] = keep + recv;
  }
}

// ---------------------------------------------------------------------------
// u_partial = b1[rows, m-range] @ x1
// grid 1024 = 256 row-groups x 4 m-splits; block 256 (4 waves, 4 rows/wave).
// wave: q = lane>>5 picks 8 of 16 cols, ml = lane&31 is the m-lane.
// LDS: 512 m x 4 float4-cols, flat-block XOR swizzle blk ^ ((m>>2)&7).
// ---------------------------------------------------------------------------
__global__ __launch_bounds__(256)
void b1_matmul_kernel(const float* __restrict__ A,   // [4096][8192]
                      const float* __restrict__ X,   // [8192][16]
                      float* __restrict__ pP)        // [4][4096][16]
{
  __shared__ float4 Bs[2048];                        // 32 KiB
  const int tid  = threadIdx.x;
  const int wv   = tid >> 6;
  const int lane = tid & 63;
  const int q    = lane >> 5;
  const int ml   = lane & 31;
  const int s    = blockIdx.x & 3;
  const int rg   = blockIdx.x >> 2;
  const int row0 = rg * 16 + wv * 4;

  float acc[32];
  #pragma unroll
  for (int i = 0; i < 32; ++i) acc[i] = 0.0f;
  const int j0 = q * 2;
  const int jj = tid & 3;        // stage col-block (constant per thread)
  const int mt = tid >> 2;       // stage m base

  for (int ch = 0; ch < 4; ++ch) {
    const int mb = s * 2048 + ch * 512;
    __syncthreads();
    #pragma unroll
    for (int k = 0; k < 8; ++k) {
      const int m = mt + 64 * k;
      Bs[(m * 4 + jj) ^ ((m >> 2) & 7)] =
          *(const float4*)(X + (size_t)(mb + m) * 16 + jj * 4);
    }
    __syncthreads();
    #pragma unroll
    for (int it = 0; it < 4; ++it) {
      const int mloc = it * 128 + ml * 4;
      float a[4][4];
      #pragma unroll
      for (int r = 0; r < 4; ++r) {
        const float4 t4 = *(const float4*)(A + (size_t)(row0 + r) * NM1 + mb + mloc);
        a[r][0] = t4.x; a[r][1] = t4.y; a[r][2] = t4.z; a[r][3] = t4.w;
      }
      #pragma unroll
      for (int v = 0; v < 4; ++v) {
        const int mm = mloc + v;
        const int h = (mm >> 2) & 7;
        const float4 b0  = Bs[(mm * 4 + j0) ^ h];
        const float4 b1v = Bs[(mm * 4 + j0 + 1) ^ h];
        #pragma unroll
        for (int r = 0; r < 4; ++r) {
          const float av = a[r][v];
          acc[r*8+0] += av * b0.x;   acc[r*8+1] += av * b0.y;
          acc[r*8+2] += av * b0.z;   acc[r*8+3] += av * b0.w;
          acc[r*8+4] += av * b1v.x;  acc[r*8+5] += av * b1v.y;
          acc[r*8+6] += av * b1v.z;  acc[r*8+7] += av * b1v.w;
        }
      }
    }
  }

  // reduce across 32 m-lanes: 32 vals -> 1 per lane
  red_scatter<16>(acc, 1, lane);
  red_scatter<8>(acc, 2, lane);
  red_scatter<4>(acc, 4, lane);
  red_scatter<2>(acc, 8, lane);
  red_scatter<1>(acc, 16, lane);

  const int r = 2 * (ml & 1) + ((ml >> 1) & 1);
  const int c = 4 * ((ml >> 2) & 1) + 2 * ((ml >> 3) & 1) + ((ml >> 4) & 1);
  pP[(size_t)(s * N0 + row0 + r) * 16 + q * 8 + c] = acc[0];
}

__global__ void finalize_u_kernel(const float* __restrict__ pP,
                                  float* __restrict__ u) {
  const int idx = blockIdx.x * 256 + threadIdx.x;   // < 65536
  u[idx] = pP[idx] + pP[65536 + idx] + pP[131072 + idx] + pP[196608 + idx];
}

// ---------------------------------------------------------------------------
// Fused Chebyshev step partials, both chains at once:
//   pX/pU[s] = L0[rows, m-range] @ {cx, cu};  pRS[s] = rowsum (step 1 only).
// grid 1024 = 256 row-groups x 4 m-splits; block 256 (4 waves, 4 rows/wave).
// wave: q = lane>>4 picks 8 of the 32 concat cols, ml = lane&15 m-lane.
// LDS: 256 m x 8 float4-cols, swizzle j ^ ((m>>2)&7).
// ---------------------------------------------------------------------------
template<bool RS>
__global__ __launch_bounds__(256)
void cheb_step_kernel(const float* __restrict__ A,    // [4096][4096]
                      const float* __restrict__ cx,   // [4096][16]
                      const float* __restrict__ cu,   // [4096][16]
                      float* __restrict__ pX,         // [4][4096][16]
                      float* __restrict__ pU,         // [4][4096][16]
                      float* __restrict__ pRS)        // [4][4096]
{
  __shared__ float4 Bs[2048];                         // 32 KiB
  const int tid  = threadIdx.x;
  const int wv   = tid >> 6;
  const int lane = tid & 63;
  const int q    = lane >> 4;
  const int ml   = lane & 15;
  const int s    = blockIdx.x & 3;
  const int rg   = blockIdx.x >> 2;
  const int row0 = rg * 16 + wv * 4;

  float acc[32];
  #pragma unroll
  for (int i = 0; i < 32; ++i) acc[i] = 0.0f;
  float rs[4] = {0.0f, 0.0f, 0.0f, 0.0f};
  const int j0 = q * 2;

  const int jj   = tid & 7;                 // stage col-block (const/thread)
  const int mt   = tid >> 3;                // stage m base
  const float* sbase = (jj < 4) ? cx : cu;
  const int joff = (jj & 3) * 4;

  for (int ch = 0; ch < 4; ++ch) {
    const int mb = s * 1024 + ch * 256;
    __syncthreads();
    #pragma unroll
    for (int k = 0; k < 8; ++k) {
      const int m = mt + 32 * k;
      Bs[(m * 8 + jj) ^ ((m >> 2) & 7)] =
          *(const float4*)(sbase + (size_t)(mb + m) * 16 + joff);
    }
    __syncthreads();
    #pragma unroll
    for (int it = 0; it < 4; ++it) {
      const int mloc = it * 64 + ml * 4;
      float a[4][4];
      #pragma unroll
      for (int r = 0; r < 4; ++r) {
        const float4 t4 = *(const float4*)(A + (size_t)(row0 + r) * N0 + mb + mloc);
        a[r][0] = t4.x; a[r][1] = t4.y; a[r][2] = t4.z; a[r][3] = t4.w;
      }
      #pragma unroll
      for (int v = 0; v < 4; ++v) {
        const int mm = mloc + v;
        const int h = (mm >> 2) & 7;
        const float4 b0  = Bs[(mm * 8 + j0) ^ h];
        const float4 b1v = Bs[(mm * 8 + j0 + 1) ^ h];
        #pragma unroll
        for (int r = 0; r < 4; ++r) {
          const float av = a[r][v];
          acc[r*8+0] += av * b0.x;   acc[r*8+1] += av * b0.y;
          acc[r*8+2] += av * b0.z;   acc[r*8+3] += av * b0.w;
          acc[r*8+4] += av * b1v.x;  acc[r*8+5] += av * b1v.y;
          acc[r*8+6] += av * b1v.z;  acc[r*8+7] += av * b1v.w;
          if constexpr (RS) rs[r] += av;
        }
      }
    }
  }

  // reduce across 16 m-lanes: 32 vals -> 2 per lane
  red_scatter<16>(acc, 1, lane);
  red_scatter<8>(acc, 2, lane);
  red_scatter<4>(acc, 4, lane);
  red_scatter<2>(acc, 8, lane);

  const int r  = 2 * (ml & 1) + ((ml >> 1) & 1);
  const int cL = 4 * ((ml >> 2) & 1) + 2 * ((ml >> 3) & 1);
  float* base = (q >> 1) ? pU : pX;
  float* dst = base + (size_t)(s * N0 + row0 + r) * 16 + (q & 1) * 8 + cL;
  *(float2*)dst = make_float2(acc[0], acc[1]);

  if constexpr (RS) {
    red_scatter<2>(rs, 1, lane);
    red_scatter<1>(rs, 2, lane);
    float rsum = rs[0] + __shfl_xor(rs[0], 4);
    rsum += __shfl_xor(rsum, 8);
    if (q == 0 && ml < 4) pRS[s * N0 + row0 + r] = rsum;
  }
}

// ---------------------------------------------------------------------------
// norm1: inv = 1/sum(pRS) (nonfinite->0), store inv; normalize step-1 partials.
// ---------------------------------------------------------------------------
__global__ void norm1_kernel(const float* __restrict__ pX,
                             const float* __restrict__ pU,
                             const float* __restrict__ pRS,
                             float* __restrict__ inv,
                             float* __restrict__ ox,
                             float* __restrict__ ou) {
  const int idx = blockIdx.x * 256 + threadIdx.x;   // < 65536
  const int row = idx >> 4;
  float rsv = pRS[row] + pRS[N0 + row] + pRS[2 * N0 + row] + pRS[3 * N0 + row];
  float iv = 1.0f / rsv;
  if (!isfinite(iv)) iv = 0.0f;
  if ((idx & 15) == 0) inv[row] = iv;
  float xv = (pX[idx] + pX[65536 + idx] + pX[131072 + idx] + pX[196608 + idx]) * iv;
  float uv = (pU[idx] + pU[65536 + idx] + pU[131072 + idx] + pU[196608 + idx]) * iv;
  ox[idx] = isfinite(xv) ? xv : 0.0f;
  ou[idx] = isfinite(uv) ? uv : 0.0f;
}

__global__ void norm23_kernel(const float* __restrict__ pX,
                              const float* __restrict__ pU,
                              const float* __restrict__ inv,
                              float* __restrict__ ox,
                              float* __restrict__ ou) {
  const int idx = blockIdx.x * 256 + threadIdx.x;   // < 65536
  const float iv = inv[idx >> 4];
  float xv = (pX[idx] + pX[65536 + idx] + pX[131072 + idx] + pX[196608 + idx]) * iv;
  float uv = (pU[idx] + pU[65536 + idx] + pU[131072 + idx] + pU[196608 + idx]) * iv;
  ox[idx] = isfinite(xv) ? xv : 0.0f;
  ou[idx] = isfinite(uv) ? uv : 0.0f;
}

// ---------------------------------------------------------------------------
// y0[n,o] = sum_{i,k} xall[n,i,k] * W[i,o,k]; k: 0=x0, 1..3=xlap, 4=u, 5..7=ulap.
// Step-3 normalization (k=3, k=7) fused from partials. block 16 rows x 16 o.
// ---------------------------------------------------------------------------
__global__ void einsum_kernel(const float* __restrict__ x0,
                              const float* __restrict__ xl1,
                              const float* __restrict__ xl2,
                              const float* __restrict__ u,
                              const float* __restrict__ ul1,
                              const float* __restrict__ ul2,
                              const float* __restrict__ pX,
                              const float* __restrict__ pU,
                              const float* __restrict__ inv,
                              const float* __restrict__ W,   // [16][16][8]
                              float* __restrict__ y) {
  __shared__ float Wl[2048];
  __shared__ float xs[16 * 128];                 // [r][k][i]
  const int t = threadIdx.x;
  const int row0 = blockIdx.x * 16;
  #pragma unroll
  for (int k = 0; k < 8; ++k) Wl[t + 256 * k] = W[t + 256 * k];
  const int r = t >> 4;
  const int i = t & 15;
  const int g = (row0 + r) * 16 + i;
  const float iv = inv[row0 + r];
  float x3 = (pX[g] + pX[65536 + g] + pX[131072 + g] + pX[196608 + g]) * iv;
  float u3 = (pU[g] + pU[65536 + g] + pU[131072 + g] + pU[196608 + g]) * iv;
  if (!isfinite(x3)) x3 = 0.0f;
  if (!isfinite(u3)) u3 = 0.0f;
  xs[r * 128 + 0 * 16 + i] = x0[g];
  xs[r * 128 + 1 * 16 + i] = xl1[g];
  xs[r * 128 + 2 * 16 + i] = xl2[g];
  xs[r * 128 + 3 * 16 + i] = x3;
  xs[r * 128 + 4 * 16 + i] = u[g];
  xs[r * 128 + 5 * 16 + i] = ul1[g];
  xs[r * 128 + 6 * 16 + i] = ul2[g];
  xs[r * 128 + 7 * 16 + i] = u3;
  __syncthreads();
  const int o = t & 15;
  float acc = 0.0f;
  #pragma unroll
  for (int ii = 0; ii < 16; ++ii) {
    #pragma unroll
    for (int k = 0; k < 8; ++k)
      acc += xs[r * 128 + k * 16 + ii] * Wl[(ii * 16 + o) * 8 + k];
  }
  y[(row0 + r) * 16 + o] = acc;
}

// ---------------------------------------------------------------------------
extern "C" void kernel_launch(void* const* d_in, const int* in_sizes, int n_in,
                              void* d_out, int out_size, void* d_ws, size_t ws_size,
                              hipStream_t stream) {
  const float* x0 = (const float*)d_in[0];
  const float* x1 = (const float*)d_in[1];
  const float* L0 = (const float*)d_in[3];
  const float* B1 = (const float*)d_in[8];
  const float* W0 = (const float*)d_in[10];

  float* ws  = (float*)d_ws;
  float* u   = ws;                 // 65536
  float* xl1 = ws + 65536;
  float* xl2 = ws + 131072;
  float* ul1 = ws + 196608;
  float* ul2 = ws + 262144;
  float* inv = ws + 327680;        // 4096
  float* pX  = ws + 331776;        // 4*65536
  float* pU  = ws + 593920;        // 4*65536
  float* pRS = ws + 856064;        // 4*4096

  // u = b1 @ x_1
  b1_matmul_kernel<<<1024, 256, 0, stream>>>(B1, x1, pX);
  finalize_u_kernel<<<256, 256, 0, stream>>>(pX, u);

  // step 1 (computes rowsum -> inv)
  cheb_step_kernel<true><<<1024, 256, 0, stream>>>(L0, x0, u, pX, pU, pRS);
  norm1_kernel<<<256, 256, 0, stream>>>(pX, pU, pRS, inv, xl1, ul1);
  // step 2
  cheb_step_kernel<false><<<1024, 256, 0, stream>>>(L0, xl1, ul1, pX, pU, pRS);
  norm23_kernel<<<256, 256, 0, stream>>>(pX, pU, inv, xl2, ul2);
  // step 3 (normalization fused into einsum)
  cheb_step_kernel<false><<<1024, 256, 0, stream>>>(L0, xl2, ul2, pX, pU, pRS);

  // y_0 = einsum('nik,iok->no', x_0_all, weight_0)
  einsum_kernel<<<256, 256, 0, stream>>>(x0, xl1, xl2, u, ul1, ul2,
                                         pX, pU, inv, W0, (float*)d_out);
}